// Round 1
// baseline (350.004 us; speedup 1.0000x reference)
//
#include <hip/hip_runtime.h>
#include <math.h>

// Problem constants
#define SEQ   4096
#define DIM   512
#define BW    24            // band half-width: prior underflows fp32 beyond |i-j|~20
#define NDIAG 49            // 2*BW+1
#define VSTR  4608          // padded row stride for band/vectors (4096 + 512)
#define VOFF  256           // data offset inside padded row (zeros on both sides)
#define INV_N (1.0f/4096.0f)

// ws layout in floats
#define OFF_GB   0                         // P@B, R@B : 2 x 4096 x 512
#define SZ_GB    (2*SEQ*DIM)
#define OFF_KB   (OFF_GB + SZ_GB)          // K band, 2 groups x 49 x VSTR
#define SZ_BAND  (2*NDIAG*VSTR)
#define OFF_DB   (OFF_KB + SZ_BAND)        // dist band
#define OFF_VEC  (OFF_DB + SZ_BAND)        // 6 padded vectors: u(g0,g1), y(g0,g1), v(g0,g1)
#define SZ_VEC   (6*VSTR)
#define OFF_PX   (OFF_VEC + SZ_VEC)        // pMp for P,Q,R,S : 4 x 4096
#define SZ_PX    (4*SEQ)
#define OFF_SC   (OFF_PX + SZ_PX)          // scalars: [0,1]=crit g0/g1, [2,3]=S g0/g1
#define SZ_SC    16
#define OFF_B    (OFF_SC + SZ_SC)          // B = M + M^T : 512x512
#define SZ_B     (DIM*DIM)
#define WS_FLOATS (OFF_B + SZ_B)

// ---------------- B = M + M^T ----------------
__global__ void ksym(const float* __restrict__ M, float* __restrict__ B) {
    int idx = blockIdx.x * 256 + threadIdx.x;       // 512*512 / 256 = 1024 blocks
    int d = idx >> 9, e = idx & 511;
    B[idx] = M[d*DIM + e] + M[e*DIM + d];
}

// ---------------- GB[z/2] = X_z @ B (store z=0,2), pX[z] = 0.5*rowdot(X, X@B) ----------------
__launch_bounds__(256)
__global__ void kgemm(const float* __restrict__ P, const float* __restrict__ Q,
                      const float* __restrict__ R, const float* __restrict__ S,
                      const float* __restrict__ B, float* __restrict__ GB,
                      float* __restrict__ pX) {
    int z = blockIdx.z;
    const float* X = (z==0) ? P : (z==1) ? Q : (z==2) ? R : S;
    int i0 = blockIdx.y * 128;
    int j0 = blockIdx.x * 128;
    __shared__ float As[16][128];   // k-major A tile
    __shared__ float Bs[16][128];
    int tid = threadIdx.x;
    int ty = tid >> 4, tx = tid & 15;
    float acc[2][2][4][4];
    #pragma unroll
    for (int a=0;a<2;a++){
        #pragma unroll
        for(int b=0;b<2;b++){
            #pragma unroll
            for(int r=0;r<4;r++){
                #pragma unroll
                for(int c=0;c<4;c++) acc[a][b][r][c]=0.f;
            }
        }
    }
    for (int kc = 0; kc < DIM; kc += 16) {
        __syncthreads();
        #pragma unroll
        for (int l = 0; l < 2; ++l) {
            int idx = tid + l*256;
            int row = idx >> 2, ko = (idx & 3) << 2;
            float4 v = *reinterpret_cast<const float4*>(&X[(size_t)(i0+row)*DIM + kc + ko]);
            As[ko+0][row]=v.x; As[ko+1][row]=v.y; As[ko+2][row]=v.z; As[ko+3][row]=v.w;
        }
        #pragma unroll
        for (int l = 0; l < 2; ++l) {
            int idx = tid + l*256;
            int kk = idx >> 5, jo = (idx & 31) << 2;
            *reinterpret_cast<float4*>(&Bs[kk][jo]) =
                *reinterpret_cast<const float4*>(&B[(size_t)(kc+kk)*DIM + j0 + jo]);
        }
        __syncthreads();
        #pragma unroll
        for (int kk = 0; kk < 16; ++kk) {
            float a[2][4], b[2][4];
            *reinterpret_cast<float4*>(a[0]) = *reinterpret_cast<const float4*>(&As[kk][ty*4]);
            *reinterpret_cast<float4*>(a[1]) = *reinterpret_cast<const float4*>(&As[kk][ty*4+64]);
            *reinterpret_cast<float4*>(b[0]) = *reinterpret_cast<const float4*>(&Bs[kk][tx*4]);
            *reinterpret_cast<float4*>(b[1]) = *reinterpret_cast<const float4*>(&Bs[kk][tx*4+64]);
            #pragma unroll
            for (int ri=0;ri<2;ri++){
                #pragma unroll
                for (int r=0;r<4;r++){
                    #pragma unroll
                    for (int ci=0;ci<2;ci++){
                        #pragma unroll
                        for (int c=0;c<4;c++)
                            acc[ri][ci][r][c] = fmaf(a[ri][r], b[ci][c], acc[ri][ci][r][c]);
                    }
                }
            }
        }
    }
    float rowp[2][4] = {{0,0,0,0},{0,0,0,0}};
    #pragma unroll
    for (int ri=0;ri<2;ri++){
        #pragma unroll
        for (int r=0;r<4;r++) {
            int i = i0 + ty*4 + ri*64 + r;
            #pragma unroll
            for (int ci=0;ci<2;ci++) {
                float4 xv = *reinterpret_cast<const float4*>(&X[(size_t)i*DIM + j0 + tx*4 + ci*64]);
                float* ac = acc[ri][ci][r];
                rowp[ri][r] += ac[0]*xv.x + ac[1]*xv.y + ac[2]*xv.z + ac[3]*xv.w;
                if ((z & 1) == 0)
                    *reinterpret_cast<float4*>(&GB[((size_t)(z>>1)*SEQ + i)*DIM + j0 + tx*4 + ci*64]) =
                        *reinterpret_cast<float4*>(ac);
            }
        }
    }
    #pragma unroll
    for (int ri=0;ri<2;ri++){
        #pragma unroll
        for (int r=0;r<4;r++) {
            float v = rowp[ri][r];
            for (int s=8;s>0;s>>=1) v += __shfl_down(v, s, 16);
            if (tx == 0) atomicAdd(&pX[(size_t)z*SEQ + i0 + ty*4 + ri*64 + r], 0.5f*v);
        }
    }
}

// ---------------- band: dist & K on 49 diagonals (diag-major, padded, pads pre-zeroed) ----------------
__launch_bounds__(128)
__global__ void kband(const float* __restrict__ Q, const float* __restrict__ S,
                      const float* __restrict__ GB, const float* __restrict__ pX,
                      float* __restrict__ Kb, float* __restrict__ Db) {
    int g = blockIdx.y;
    const float* Y  = g ? S : Q;
    const float* PB = GB + (size_t)g*SEQ*DIM;
    const float* pM = pX + (size_t)(2*g)*SEQ;
    const float* qM = pX + (size_t)(2*g+1)*SEQ;
    float* Kbg = Kb + (size_t)g*NDIAG*VSTR;
    float* Dbg = Db + (size_t)g*NDIAG*VSTR;
    int i0 = blockIdx.x * 64;
    __shared__ float PBs[32][64];
    __shared__ float Ys[32][112];
    int tid = threadIdx.x;
    int my = tid >> 4;           // 0..7 -> rows my*4 (+{0..3}), my*4+32
    int mx = tid & 15;           // 0..13 used -> cols mx*4, mx*4+56
    float acc[2][2][4][4];
    #pragma unroll
    for (int a=0;a<2;a++){
        #pragma unroll
        for(int b=0;b<2;b++){
            #pragma unroll
            for(int r=0;r<4;r++){
                #pragma unroll
                for(int c=0;c<4;c++) acc[a][b][r][c]=0.f;
            }
        }
    }
    for (int kc = 0; kc < DIM; kc += 32) {
        __syncthreads();
        #pragma unroll
        for (int l = 0; l < 4; ++l) {
            int idx = tid + l*128;
            int row = idx >> 3, ko = (idx & 7) << 2;
            float4 v = *reinterpret_cast<const float4*>(&PB[(size_t)(i0+row)*DIM + kc + ko]);
            PBs[ko+0][row]=v.x; PBs[ko+1][row]=v.y; PBs[ko+2][row]=v.z; PBs[ko+3][row]=v.w;
        }
        #pragma unroll
        for (int l = 0; l < 7; ++l) {
            int idx = tid + l*128;
            int row = idx >> 3, ko = (idx & 7) << 2;
            int gx = i0 - BW + row;
            float4 v = make_float4(0.f,0.f,0.f,0.f);
            if (gx >= 0 && gx < SEQ)
                v = *reinterpret_cast<const float4*>(&Y[(size_t)gx*DIM + kc + ko]);
            Ys[ko+0][row]=v.x; Ys[ko+1][row]=v.y; Ys[ko+2][row]=v.z; Ys[ko+3][row]=v.w;
        }
        __syncthreads();
        if (mx < 14) {
            #pragma unroll
            for (int kk = 0; kk < 32; ++kk) {
                float a[2][4], b[2][4];
                *reinterpret_cast<float4*>(a[0]) = *reinterpret_cast<const float4*>(&PBs[kk][my*4]);
                *reinterpret_cast<float4*>(a[1]) = *reinterpret_cast<const float4*>(&PBs[kk][my*4+32]);
                *reinterpret_cast<float4*>(b[0]) = *reinterpret_cast<const float4*>(&Ys[kk][mx*4]);
                *reinterpret_cast<float4*>(b[1]) = *reinterpret_cast<const float4*>(&Ys[kk][mx*4+56]);
                #pragma unroll
                for (int ri=0;ri<2;ri++){
                    #pragma unroll
                    for (int r=0;r<4;r++){
                        #pragma unroll
                        for (int ci=0;ci<2;ci++){
                            #pragma unroll
                            for (int c=0;c<4;c++)
                                acc[ri][ci][r][c] = fmaf(a[ri][r], b[ci][c], acc[ri][ci][r][c]);
                        }
                    }
                }
            }
        }
    }
    if (mx < 14) {
        #pragma unroll
        for (int ri=0;ri<2;ri++){
            #pragma unroll
            for (int r=0;r<4;r++) {
                int il = my*4 + ri*32 + r;
                int i = i0 + il;
                float pmi = pM[i];
                #pragma unroll
                for (int ci=0;ci<2;ci++){
                    #pragma unroll
                    for (int c=0;c<4;c++) {
                        int xl = mx*4 + ci*56 + c;
                        int gx = i0 - BW + xl;
                        int d = xl - il - BW;
                        if (d >= -BW && d <= BW && gx >= 0 && gx < SEQ) {
                            float dist = pmi + qM[gx] - acc[ri][ci][r][c];
                            float fd = (float)d;
                            float rel = fd * (1.0f/4096.0f);
                            // K = 1/sqrt(2pi) * exp(-d^2/4) * exp(-(dist - 0.1/(rel^2+1))/1000)
                            float cd = -0.91893853f - 0.25f*fd*fd + 1e-4f/(rel*rel + 1.0f);
                            float Kv = expf(cd - dist*1e-3f);
                            int idx = d + BW;
                            Dbg[(size_t)idx*VSTR + VOFF + i] = dist;
                            Kbg[(size_t)idx*VSTR + VOFF + i] = Kv;
                        }
                    }
                }
            }
        }
    }
}

// ---------------- Sinkhorn: fused banded matvec chain with halo compute (no grid sync) ----
// step type T:  out[j] = beta_j / sum_idx Kb[idx][j-idx+BW] * in[j-idx+BW]   (Kt matvec)
// step type N:  out[i] = alpha_i / sum_idx Kb[idx][i] * in[i+idx-BW]         (K matvec)
// vstep: at that step also store result to v slot. cstep: crit step (raw t3, no halo, nsteps==1).
__launch_bounds__(256)
__global__ void ksink(const float* __restrict__ Kb, float* __restrict__ vecs,
                      float* __restrict__ sc,
                      int nsteps, int firstT, int alphaInit,
                      int vstep, int cstep, int gated, int inSlot, int outSlot) {
    int g = blockIdx.y;
    if (gated && sc[g] < 1e-5f) return;   // early-converged: freeze u,v
    const float* Kbg = Kb + (size_t)g * NDIAG * VSTR;
    int r0 = blockIdx.x * 256;
    int ext = 24 * nsteps;                // input halo
    __shared__ float bufA[704];
    __shared__ float bufB[704];
    __shared__ float red[256];
    float* bin = bufA;
    float* bout = bufB;
    int base = r0 - ext;
    int range0 = 256 + 2*ext;
    const float* vin = vecs + (size_t)(inSlot*2 + g) * VSTR;
    for (int L = threadIdx.x; L < range0; L += 256) {
        int gr = base + L;
        float v;
        if (alphaInit) v = (gr >= 0 && gr < SEQ) ? (gr+1)*INV_N : 0.f;
        else v = vin[VOFF + gr];
        bufA[L] = v;
    }
    __syncthreads();
    float critloc = 0.f;
    for (int m = 0; m < nsteps; ++m) {
        int e = 24 * (nsteps - 1 - m);
        int lo = ext - e;
        int cnt = 256 + 2*e;
        int typeT = firstT ^ (m & 1);
        for (int t = threadIdx.x; t < cnt; t += 256) {
            int L = lo + t;
            int gr = base + L;
            float s = 0.f;
            if (typeT) {
                #pragma unroll
                for (int idx = 0; idx < NDIAG; ++idx)
                    s = fmaf(Kbg[(size_t)idx*VSTR + VOFF + gr - idx + BW], bin[L - idx + BW], s);
            } else {
                #pragma unroll
                for (int idx = 0; idx < NDIAG; ++idx)
                    s = fmaf(Kbg[(size_t)idx*VSTR + VOFF + gr], bin[L + idx - BW], s);
            }
            bool valid = (gr >= 0 && gr < SEQ);
            float ab = (gr+1) * INV_N;     // alpha == beta (m==n)
            float o = valid ? ab / s : 0.f;
            bout[L] = o;
            if (m == vstep && valid)
                vecs[(size_t)(4 + g)*VSTR + VOFF + gr] = o;      // v slot
            if (m == cstep && valid) {
                float v2 = vecs[(size_t)(4 + g)*VSTR + VOFF + gr];
                critloc += fabsf(v2 * s - ab);
            }
        }
        __syncthreads();
        float* tmp = bin; bin = bout; bout = tmp;
    }
    // write own rows of final vector
    {
        int gr = r0 + threadIdx.x;
        vecs[(size_t)(outSlot*2 + g)*VSTR + VOFF + gr] = bin[ext + threadIdx.x];
    }
    if (cstep >= 0) {
        red[threadIdx.x] = critloc;
        __syncthreads();
        for (int s = 128; s > 0; s >>= 1) {
            if (threadIdx.x < s) red[threadIdx.x] += red[threadIdx.x + s];
            __syncthreads();
        }
        if (threadIdx.x == 0) atomicAdd(&sc[g], red[0]);
    }
}

// ---------------- final: S_g = sum u_i * K[i,j] * v_j * dist[i,j] over band ----------------
__launch_bounds__(256)
__global__ void kfinal(const float* __restrict__ Kb, const float* __restrict__ Db,
                       const float* __restrict__ vecs, float* __restrict__ sc) {
    int g = blockIdx.y;
    int i = blockIdx.x * 256 + threadIdx.x;
    const float* Kbg = Kb + (size_t)g*NDIAG*VSTR;
    const float* Dbg = Db + (size_t)g*NDIAG*VSTR;
    const float* u = vecs + (size_t)(0 + g)*VSTR + VOFF;
    const float* v = vecs + (size_t)(4 + g)*VSTR + VOFF;
    float ui = u[i];
    float ss = 0.f;
    #pragma unroll
    for (int idx = 0; idx < NDIAG; ++idx) {
        float kv = Kbg[(size_t)idx*VSTR + VOFF + i];
        float dv = Dbg[(size_t)idx*VSTR + VOFF + i];
        float vv = v[i + idx - BW];
        ss += kv * dv * vv;
    }
    ss *= ui;
    __shared__ float red[256];
    red[threadIdx.x] = ss;
    __syncthreads();
    for (int s = 128; s > 0; s >>= 1) {
        if (threadIdx.x < s) red[threadIdx.x] += red[threadIdx.x + s];
        __syncthreads();
    }
    if (threadIdx.x == 0) atomicAdd(&sc[2+g], red[0]);
}

__global__ void kout(const float* __restrict__ sc, float* __restrict__ out) {
    out[0] = sc[2] - sc[3];
}

extern "C" void kernel_launch(void* const* d_in, const int* in_sizes, int n_in,
                              void* d_out, int out_size, void* d_ws, size_t ws_size,
                              hipStream_t stream) {
    const float* P = (const float*)d_in[0];
    const float* Q = (const float*)d_in[1];
    const float* R = (const float*)d_in[2];
    const float* S = (const float*)d_in[3];
    const float* M = (const float*)d_in[4];
    float* ws = (float*)d_ws;
    if (ws_size < (size_t)WS_FLOATS * sizeof(float)) return;

    float* GB  = ws + OFF_GB;
    float* Kb  = ws + OFF_KB;
    float* Db  = ws + OFF_DB;
    float* vec = ws + OFF_VEC;
    float* pX  = ws + OFF_PX;
    float* sc  = ws + OFF_SC;
    float* B   = ws + OFF_B;

    // zero bands, vectors, pX, scalars (pads must be 0; pX/sc accumulated atomically)
    hipMemsetAsync(ws + OFF_KB, 0, (size_t)(OFF_B - OFF_KB) * sizeof(float), stream);

    ksym <<<dim3(1024),      dim3(256), 0, stream>>>(M, B);
    kgemm<<<dim3(4, 32, 4),  dim3(256), 0, stream>>>(P, Q, R, S, B, GB, pX);
    kband<<<dim3(64, 2),     dim3(128), 0, stream>>>(Q, S, GB, pX, Kb, Db);

    // Sinkhorn (42 banded matvecs). Slots: 0=u, 1=y, 2=v.
    //                                    nst fT aI  vs  cs gt in out
    ksink<<<dim3(16,2),256,0,stream>>>(Kb,vec,sc, 2, 1, 1, -1, -1, 0, 0, 0); // body1: T,N -> u1
    ksink<<<dim3(16,2),256,0,stream>>>(Kb,vec,sc, 2, 1, 0,  0, -1, 0, 0, 0); // check1: v2(stored), u2
    ksink<<<dim3(16,2),256,0,stream>>>(Kb,vec,sc, 1, 1, 0, -1,  0, 0, 0, 1); // crit1: t3 -> y=beta/t3
    ksink<<<dim3(16,2),256,0,stream>>>(Kb,vec,sc, 8, 0, 0, -1, -1, 1, 1, 1); // bodies (N,T)x4
    ksink<<<dim3(16,2),256,0,stream>>>(Kb,vec,sc, 8, 0, 0, -1, -1, 1, 1, 1);
    ksink<<<dim3(16,2),256,0,stream>>>(Kb,vec,sc, 8, 0, 0, -1, -1, 1, 1, 1);
    ksink<<<dim3(16,2),256,0,stream>>>(Kb,vec,sc, 8, 0, 0, -1, -1, 1, 1, 1);
    ksink<<<dim3(16,2),256,0,stream>>>(Kb,vec,sc, 5, 0, 0,  3, -1, 1, 1, 0); // last bodies + check2: v2', u2'

    kfinal<<<dim3(16,2), dim3(256), 0, stream>>>(Kb, Db, vec, sc);
    kout  <<<dim3(1),    dim3(1),   0, stream>>>(sc, (float*)d_out);
}

// Round 2
// 277.158 us; speedup vs baseline: 1.2628x; 1.2628x over previous
//
#include <hip/hip_runtime.h>
#include <math.h>

// Problem constants
#define SEQ   4096
#define DIM   512
#define BW    24            // band half-width: prior underflows fp32 beyond |i-j|~20
#define NDIAG 49            // 2*BW+1
#define VSTR  4608          // padded row stride for band/vectors (4096 + 512)
#define VOFF  256           // data offset inside padded row (zeros on both sides)
#define INV_N (1.0f/4096.0f)

// ws layout in floats
#define OFF_KB   0                          // K band, 2 groups x 49 x VSTR
#define SZ_BAND  (2*NDIAG*VSTR)             // 451584
#define OFF_DB   (OFF_KB + SZ_BAND)         // dist band
#define OFF_VEC  (OFF_DB + SZ_BAND)         // 6 padded vectors: u(g0,g1), y(g0,g1), v(g0,g1)
#define SZ_VEC   (6*VSTR)
#define OFF_PX   (OFF_VEC + SZ_VEC)         // pMp for P,Q,R,S : 4 x 4096
#define SZ_PX    (4*SEQ)
#define OFF_SC   (OFF_PX + SZ_PX)           // scalars: [0,1]=crit g0/g1, [2,3]=S g0/g1
#define SZ_SC    16
#define OFF_BBF  (OFF_SC + SZ_SC)           // Bsym bf16 512x512      (131072 floats)
#define SZ_BBF   (DIM*DIM/2)
#define OFF_QBF  (OFF_BBF + SZ_BBF)         // Q,S bf16 2x4096x512    (2097152 floats)
#define SZ_QBF   (2*SEQ*DIM/2)
#define OFF_GBF  (OFF_QBF + SZ_QBF)         // P@B, R@B bf16          (2097152 floats)
#define SZ_GBF   (2*SEQ*DIM/2)
#define WS_FLOATS (OFF_GBF + SZ_GBF)        // ~21.1 MB

typedef __attribute__((ext_vector_type(8))) short short8;
typedef __attribute__((ext_vector_type(4))) float f32x4;

__device__ __forceinline__ ushort f2bf(float f) {
    union { float f; unsigned u; } v; v.f = f;
    unsigned u = v.u;
    return (ushort)((u + 0x7FFFu + ((u >> 16) & 1u)) >> 16);
}

// ---------------- Bbf = bf16(M + M^T) ----------------
__global__ void ksym2(const float* __restrict__ M, ushort* __restrict__ Bbf) {
    int idx = blockIdx.x * 256 + threadIdx.x;       // 1024 blocks
    int d = idx >> 9, e = idx & 511;
    Bbf[idx] = f2bf(M[d*DIM + e] + M[e*DIM + d]);
}

// ---------------- Qbf = bf16(Q), Sbf = bf16(S) ----------------
__global__ void kcvt(const float* __restrict__ Q, const float* __restrict__ S,
                     ushort* __restrict__ Qbf) {
    int g = blockIdx.y;
    const float* src = g ? S : Q;
    size_t idx = ((size_t)blockIdx.x * 256 + threadIdx.x) * 4;
    float4 v = *reinterpret_cast<const float4*>(&src[idx]);
    ushort4 o;
    o.x = f2bf(v.x); o.y = f2bf(v.y); o.z = f2bf(v.z); o.w = f2bf(v.w);
    *reinterpret_cast<ushort4*>(&Qbf[(size_t)g*SEQ*DIM + idx]) = o;
}

// ---------------- bf16 MFMA GEMM: XB = bf16(X) @ Bbf; pX[z]=0.5*rowdot(Xbf,XB); GBbf for z=0,2 ----
// Bsym symmetric -> B-operand frag B[k][col] == Bbf[col][k] (row-contiguous 16B loads).
__launch_bounds__(256)
__global__ void kgemm2(const float* __restrict__ P, const float* __restrict__ Q,
                       const float* __restrict__ R, const float* __restrict__ S,
                       const ushort* __restrict__ Bbf, ushort* __restrict__ GBbf,
                       float* __restrict__ pX) {
    int z = blockIdx.y;
    const float* X = (z==0) ? P : (z==1) ? Q : (z==2) ? R : S;
    int rowbase = blockIdx.x * 64;
    __shared__ ushort Als[64*512];       // 64KB bf16 A-panel, XOR-swizzled
    int tid = threadIdx.x;
    // stage: 64 rows x 512 k, fp32 -> bf16, swizzled so MFMA frag reads are conflict-free
    #pragma unroll
    for (int c = 0; c < 16; ++c) {
        int e0 = (c*256 + tid) * 8;
        int row = e0 >> 9, k = e0 & 511;
        const float* src = &X[(size_t)(rowbase + row)*DIM + k];
        float4 v0 = *reinterpret_cast<const float4*>(src);
        float4 v1 = *reinterpret_cast<const float4*>(src + 4);
        uint4 w;
        w.x = (uint)f2bf(v0.x) | ((uint)f2bf(v0.y) << 16);
        w.y = (uint)f2bf(v0.z) | ((uint)f2bf(v0.w) << 16);
        w.z = (uint)f2bf(v1.x) | ((uint)f2bf(v1.y) << 16);
        w.w = (uint)f2bf(v1.z) | ((uint)f2bf(v1.w) << 16);
        int byte = ((row << 10) | (k << 1)) ^ ((row & 7) << 4);
        *reinterpret_cast<uint4*>(reinterpret_cast<char*>(Als) + byte) = w;
    }
    __syncthreads();
    int wv = tid >> 6, l = tid & 63;
    int rb = wv * 16;                    // wave's 16-row tile
    int arow = rb + (l & 15);
    int akoff = (l >> 4) * 8;
    float rd[4] = {0.f, 0.f, 0.f, 0.f};
    for (int jb = 0; jb < 4; ++jb) {
        int j0 = jb * 128;
        f32x4 acc[8];
        #pragma unroll
        for (int jt = 0; jt < 8; ++jt) acc[jt] = (f32x4){0.f,0.f,0.f,0.f};
        #pragma unroll
        for (int ks = 0; ks < 16; ++ks) {
            int kk = ks*32 + akoff;
            int ab = ((arow << 10) | (kk << 1)) ^ ((arow & 7) << 4);
            short8 af = *reinterpret_cast<const short8*>(
                            reinterpret_cast<const char*>(Als) + ab);
            #pragma unroll
            for (int jt = 0; jt < 8; ++jt) {
                int col = j0 + jt*16 + (l & 15);
                short8 bf = *reinterpret_cast<const short8*>(&Bbf[(size_t)col*DIM + kk]);
                acc[jt] = __builtin_amdgcn_mfma_f32_16x16x32_bf16(af, bf, acc[jt], 0, 0, 0);
            }
        }
        // epilogue: rowdot += C .* Xbf ; GBbf store (z even)
        #pragma unroll
        for (int jt = 0; jt < 8; ++jt) {
            #pragma unroll
            for (int r = 0; r < 4; ++r) {
                int row = rb + (l >> 4)*4 + r;
                int col = j0 + jt*16 + (l & 15);
                float cv = acc[jt][r];
                int xb = ((row << 10) | (col << 1)) ^ ((row & 7) << 4);
                ushort xu = *reinterpret_cast<const ushort*>(
                                reinterpret_cast<const char*>(Als) + xb);
                union { unsigned u; float f; } xc; xc.u = ((unsigned)xu) << 16;
                rd[r] = fmaf(cv, xc.f, rd[r]);
                if ((z & 1) == 0)
                    GBbf[((size_t)((z >> 1)*SEQ + rowbase + row))*DIM + col] = f2bf(cv);
            }
        }
    }
    #pragma unroll
    for (int r = 0; r < 4; ++r) {
        float v = rd[r];
        v += __shfl_xor(v, 1);
        v += __shfl_xor(v, 2);
        v += __shfl_xor(v, 4);
        v += __shfl_xor(v, 8);
        if ((l & 15) == 0)
            pX[(size_t)z*SEQ + rowbase + rb + (l >> 4)*4 + r] = 0.5f * v;
    }
}

// ---------------- band via MFMA: cross = PBbf @ Ybf^T on 49 diagonals; dist & K ----------------
__launch_bounds__(64)
__global__ void kband2(const ushort* __restrict__ GBbf, const ushort* __restrict__ Qbf,
                       const float* __restrict__ pX,
                       float* __restrict__ Kb, float* __restrict__ Db) {
    int g = blockIdx.y;
    int i0 = blockIdx.x * 16;
    int l = threadIdx.x;
    const ushort* A = GBbf + (size_t)g*SEQ*DIM;
    const ushort* Y = Qbf  + (size_t)g*SEQ*DIM;
    const float* pM = pX + (size_t)(2*g)*SEQ;
    const float* qM = pX + (size_t)(2*g+1)*SEQ;
    float* Kbg = Kb + (size_t)g*NDIAG*VSTR;
    float* Dbg = Db + (size_t)g*NDIAG*VSTR;
    int jbase = i0 - BW;
    int arow = i0 + (l & 15);
    int koff = (l >> 4) * 8;
    int jcl[4];
    #pragma unroll
    for (int ct = 0; ct < 4; ++ct) {
        int j = jbase + ct*16 + (l & 15);
        jcl[ct] = min(max(j, 0), SEQ-1);
    }
    f32x4 acc[4];
    #pragma unroll
    for (int ct = 0; ct < 4; ++ct) acc[ct] = (f32x4){0.f,0.f,0.f,0.f};
    #pragma unroll
    for (int ks = 0; ks < 16; ++ks) {
        int kk = ks*32 + koff;
        short8 af = *reinterpret_cast<const short8*>(&A[(size_t)arow*DIM + kk]);
        #pragma unroll
        for (int ct = 0; ct < 4; ++ct) {
            short8 bf = *reinterpret_cast<const short8*>(&Y[(size_t)jcl[ct]*DIM + kk]);
            acc[ct] = __builtin_amdgcn_mfma_f32_16x16x32_bf16(af, bf, acc[ct], 0, 0, 0);
        }
    }
    #pragma unroll
    for (int ct = 0; ct < 4; ++ct) {
        #pragma unroll
        for (int r = 0; r < 4; ++r) {
            int i = i0 + (l >> 4)*4 + r;
            int j = jbase + ct*16 + (l & 15);
            int d = j - i;
            if (d >= -BW && d <= BW && j >= 0 && j < SEQ) {
                float dist = pM[i] + qM[j] - acc[ct][r];
                float fd = (float)d;
                float rel = fd * (1.0f/4096.0f);
                // K = 1/sqrt(2pi) * exp(-d^2/4) * exp(-(dist - 0.1/(rel^2+1))/1000)
                float cd = -0.91893853f - 0.25f*fd*fd + 1e-4f/(rel*rel + 1.0f);
                float Kv = expf(cd - dist*1e-3f);
                Dbg[(size_t)(d + BW)*VSTR + VOFF + i] = dist;
                Kbg[(size_t)(d + BW)*VSTR + VOFF + i] = Kv;
            }
        }
    }
}

// ---------------- Sinkhorn: fused banded matvec chain with halo compute (no grid sync) ----
__launch_bounds__(256)
__global__ void ksink(const float* __restrict__ Kb, float* __restrict__ vecs,
                      float* __restrict__ sc,
                      int nsteps, int firstT, int alphaInit,
                      int vstep, int cstep, int gated, int inSlot, int outSlot) {
    int g = blockIdx.y;
    if (gated && sc[g] < 1e-5f) return;   // early-converged: freeze u,v
    const float* Kbg = Kb + (size_t)g * NDIAG * VSTR;
    int r0 = blockIdx.x * 256;
    int ext = 24 * nsteps;                // input halo
    __shared__ float bufA[704];
    __shared__ float bufB[704];
    __shared__ float red[256];
    float* bin = bufA;
    float* bout = bufB;
    int base = r0 - ext;
    int range0 = 256 + 2*ext;
    const float* vin = vecs + (size_t)(inSlot*2 + g) * VSTR;
    for (int L = threadIdx.x; L < range0; L += 256) {
        int gr = base + L;
        float v;
        if (alphaInit) v = (gr >= 0 && gr < SEQ) ? (gr+1)*INV_N : 0.f;
        else v = vin[VOFF + gr];
        bufA[L] = v;
    }
    __syncthreads();
    float critloc = 0.f;
    for (int m = 0; m < nsteps; ++m) {
        int e = 24 * (nsteps - 1 - m);
        int lo = ext - e;
        int cnt = 256 + 2*e;
        int typeT = firstT ^ (m & 1);
        for (int t = threadIdx.x; t < cnt; t += 256) {
            int L = lo + t;
            int gr = base + L;
            float s = 0.f;
            if (typeT) {
                #pragma unroll
                for (int idx = 0; idx < NDIAG; ++idx)
                    s = fmaf(Kbg[(size_t)idx*VSTR + VOFF + gr - idx + BW], bin[L - idx + BW], s);
            } else {
                #pragma unroll
                for (int idx = 0; idx < NDIAG; ++idx)
                    s = fmaf(Kbg[(size_t)idx*VSTR + VOFF + gr], bin[L + idx - BW], s);
            }
            bool valid = (gr >= 0 && gr < SEQ);
            float ab = (gr+1) * INV_N;     // alpha == beta (m==n)
            float o = valid ? ab / s : 0.f;
            bout[L] = o;
            if (m == vstep && valid)
                vecs[(size_t)(4 + g)*VSTR + VOFF + gr] = o;      // v slot
            if (m == cstep && valid) {
                float v2 = vecs[(size_t)(4 + g)*VSTR + VOFF + gr];
                critloc += fabsf(v2 * s - ab);
            }
        }
        __syncthreads();
        float* tmp = bin; bin = bout; bout = tmp;
    }
    {
        int gr = r0 + threadIdx.x;
        vecs[(size_t)(outSlot*2 + g)*VSTR + VOFF + gr] = bin[ext + threadIdx.x];
    }
    if (cstep >= 0) {
        red[threadIdx.x] = critloc;
        __syncthreads();
        for (int s = 128; s > 0; s >>= 1) {
            if (threadIdx.x < s) red[threadIdx.x] += red[threadIdx.x + s];
            __syncthreads();
        }
        if (threadIdx.x == 0) atomicAdd(&sc[g], red[0]);
    }
}

// ---------------- final: S_g = sum u_i * K[i,j] * v_j * dist[i,j] over band ----------------
__launch_bounds__(256)
__global__ void kfinal(const float* __restrict__ Kb, const float* __restrict__ Db,
                       const float* __restrict__ vecs, float* __restrict__ sc) {
    int g = blockIdx.y;
    int i = blockIdx.x * 256 + threadIdx.x;
    const float* Kbg = Kb + (size_t)g*NDIAG*VSTR;
    const float* Dbg = Db + (size_t)g*NDIAG*VSTR;
    const float* u = vecs + (size_t)(0 + g)*VSTR + VOFF;
    const float* v = vecs + (size_t)(4 + g)*VSTR + VOFF;
    float ui = u[i];
    float ss = 0.f;
    #pragma unroll
    for (int idx = 0; idx < NDIAG; ++idx) {
        float kv = Kbg[(size_t)idx*VSTR + VOFF + i];
        float dv = Dbg[(size_t)idx*VSTR + VOFF + i];
        float vv = v[i + idx - BW];
        ss += kv * dv * vv;
    }
    ss *= ui;
    __shared__ float red[256];
    red[threadIdx.x] = ss;
    __syncthreads();
    for (int s = 128; s > 0; s >>= 1) {
        if (threadIdx.x < s) red[threadIdx.x] += red[threadIdx.x + s];
        __syncthreads();
    }
    if (threadIdx.x == 0) atomicAdd(&sc[2+g], red[0]);
}

__global__ void kout(const float* __restrict__ sc, float* __restrict__ out) {
    out[0] = sc[2] - sc[3];
}

extern "C" void kernel_launch(void* const* d_in, const int* in_sizes, int n_in,
                              void* d_out, int out_size, void* d_ws, size_t ws_size,
                              hipStream_t stream) {
    const float* P = (const float*)d_in[0];
    const float* Q = (const float*)d_in[1];
    const float* R = (const float*)d_in[2];
    const float* S = (const float*)d_in[3];
    const float* M = (const float*)d_in[4];
    float* ws = (float*)d_ws;
    if (ws_size < (size_t)WS_FLOATS * sizeof(float)) return;

    float*  Kb  = ws + OFF_KB;
    float*  Db  = ws + OFF_DB;
    float*  vec = ws + OFF_VEC;
    float*  pX  = ws + OFF_PX;
    float*  sc  = ws + OFF_SC;
    ushort* Bbf = (ushort*)(ws + OFF_BBF);
    ushort* Qbf = (ushort*)(ws + OFF_QBF);
    ushort* GBbf= (ushort*)(ws + OFF_GBF);

    // zero bands, vectors, pX, scalars (pads must be 0; sc accumulated atomically)
    hipMemsetAsync(ws + OFF_KB, 0, (size_t)OFF_BBF * sizeof(float), stream);

    ksym2 <<<dim3(1024),    dim3(256), 0, stream>>>(M, Bbf);
    kcvt  <<<dim3(2048, 2), dim3(256), 0, stream>>>(Q, S, Qbf);
    kgemm2<<<dim3(64, 4),   dim3(256), 0, stream>>>(P, Q, R, S, Bbf, GBbf, pX);
    kband2<<<dim3(256, 2),  dim3(64),  0, stream>>>(GBbf, Qbf, pX, Kb, Db);

    // Sinkhorn (42 banded matvecs). Slots: 0=u, 1=y, 2=v.
    //                                    nst fT aI  vs  cs gt in out
    ksink<<<dim3(16,2),256,0,stream>>>(Kb,vec,sc, 2, 1, 1, -1, -1, 0, 0, 0); // body1: T,N -> u1
    ksink<<<dim3(16,2),256,0,stream>>>(Kb,vec,sc, 2, 1, 0,  0, -1, 0, 0, 0); // check1: v2(stored), u2
    ksink<<<dim3(16,2),256,0,stream>>>(Kb,vec,sc, 1, 1, 0, -1,  0, 0, 0, 1); // crit1: t3 -> y=beta/t3
    ksink<<<dim3(16,2),256,0,stream>>>(Kb,vec,sc, 8, 0, 0, -1, -1, 1, 1, 1); // bodies (N,T)x4
    ksink<<<dim3(16,2),256,0,stream>>>(Kb,vec,sc, 8, 0, 0, -1, -1, 1, 1, 1);
    ksink<<<dim3(16,2),256,0,stream>>>(Kb,vec,sc, 8, 0, 0, -1, -1, 1, 1, 1);
    ksink<<<dim3(16,2),256,0,stream>>>(Kb,vec,sc, 8, 0, 0, -1, -1, 1, 1, 1);
    ksink<<<dim3(16,2),256,0,stream>>>(Kb,vec,sc, 5, 0, 0,  3, -1, 1, 1, 0); // last bodies + check2

    kfinal<<<dim3(16,2), dim3(256), 0, stream>>>(Kb, Db, vec, sc);
    kout  <<<dim3(1),    dim3(1),   0, stream>>>(sc, (float*)d_out);
}

// Round 3
// 194.076 us; speedup vs baseline: 1.8034x; 1.4281x over previous
//
#include <hip/hip_runtime.h>
#include <math.h>

// Problem constants
#define SEQ   4096
#define DIM   512
#define BW    24            // band half-width: prior underflows fp32 beyond |i-j|~20
#define NDIAG 49            // 2*BW+1
#define VSTR  4608          // padded row stride for band/vectors (4096 + 512)
#define VOFF  256           // data offset inside padded row (zeros on both sides)
#define INV_N (1.0f/4096.0f)

// ws layout in floats (same as round 2, known to fit)
#define OFF_KB   0                          // K band, 2 groups x 49 x VSTR
#define SZ_BAND  (2*NDIAG*VSTR)             // 451584
#define OFF_DB   (OFF_KB + SZ_BAND)         // dist band
#define OFF_VEC  (OFF_DB + SZ_BAND)         // 6 padded vectors: u(g0,g1), y(g0,g1), v(g0,g1)
#define SZ_VEC   (6*VSTR)
#define OFF_PX   (OFF_VEC + SZ_VEC)         // pMp for P,Q,R,S : 4 x 4096
#define SZ_PX    (4*SEQ)
#define OFF_SC   (OFF_PX + SZ_PX)           // scalars: [0,1]=crit g0/g1, [2,3]=S g0/g1
#define SZ_SC    16
#define OFF_BBF  (OFF_SC + SZ_SC)           // Bsym bf16 512x512
#define SZ_BBF   (DIM*DIM/2)
#define OFF_QBF  (OFF_BBF + SZ_BBF)         // Q,S bf16 2x4096x512
#define SZ_QBF   (2*SEQ*DIM/2)
#define OFF_GBF  (OFF_QBF + SZ_QBF)         // P@B, R@B bf16
#define SZ_GBF   (2*SEQ*DIM/2)
#define WS_FLOATS (OFF_GBF + SZ_GBF)        // ~21.1 MB

typedef __attribute__((ext_vector_type(8))) short short8;
typedef __attribute__((ext_vector_type(4))) float f32x4;

__device__ __forceinline__ ushort f2bf(float f) {
    union { float f; unsigned u; } v; v.f = f;
    unsigned u = v.u;
    return (ushort)((u + 0x7FFFu + ((u >> 16) & 1u)) >> 16);
}

__device__ __forceinline__ void gload16(void* lds, const void* g) {
    __builtin_amdgcn_global_load_lds(
        (const __attribute__((address_space(1))) unsigned int*)g,
        (__attribute__((address_space(3))) unsigned int*)lds,
        16, 0, 0);
}

// ---------------- Bbf = bf16(M + M^T) ----------------
__global__ void ksym2(const float* __restrict__ M, ushort* __restrict__ Bbf) {
    int idx = blockIdx.x * 256 + threadIdx.x;
    int d = idx >> 9, e = idx & 511;
    Bbf[idx] = f2bf(M[d*DIM + e] + M[e*DIM + d]);
}

// ---------------- Qbf = bf16(Q), Sbf = bf16(S) ----------------
__global__ void kcvt(const float* __restrict__ Q, const float* __restrict__ S,
                     ushort* __restrict__ Qbf) {
    int g = blockIdx.y;
    const float* src = g ? S : Q;
    size_t idx = ((size_t)blockIdx.x * 256 + threadIdx.x) * 4;
    float4 v = *reinterpret_cast<const float4*>(&src[idx]);
    ushort4 o;
    o.x = f2bf(v.x); o.y = f2bf(v.y); o.z = f2bf(v.z); o.w = f2bf(v.w);
    *reinterpret_cast<ushort4*>(&Qbf[(size_t)g*SEQ*DIM + idx]) = o;
}

// ---------------- MFMA GEMM, 2-phase pipelined (T3 minimum recipe) ----------------
// XB = bf16(X) @ Bbf  (Bsym symmetric -> Bbf rows serve as B^T rows).
// A staged fp32 via global_load_lds with source-side XOR swizzle (T2); cvt to bf16 at frag read.
// Epilogue: pX[z] += 0.5*rowdot(X, XB) (atomics); GBbf store for z even.
__launch_bounds__(256, 2)
__global__ void kgemm3(const float* __restrict__ P, const float* __restrict__ Q,
                       const float* __restrict__ R, const float* __restrict__ S,
                       const ushort* __restrict__ Bbf, ushort* __restrict__ GBbf,
                       float* __restrict__ pX) {
    int z = blockIdx.z;
    const float* X = (z==0) ? P : (z==1) ? Q : (z==2) ? R : S;
    int i0 = blockIdx.x * 128;
    int j0 = blockIdx.y * 128;
    __shared__ float  As[2*128*32];    // 2 x 16KB, rows 128B, chunk^=(row&7)
    __shared__ ushort Bs[2*128*32];    // 2 x 8KB,  rows 64B,  chunk^=(col&3)
    int tid = threadIdx.x, wv = tid >> 6, l = tid & 63;
    int h = l >> 4, lr = l & 15;
    int wrow = (wv >> 1) * 64, wcol = (wv & 1) * 64;

    auto stage = [&](int buf, int kc) {
        #pragma unroll
        for (int s2 = 0; s2 < 4; ++s2) {          // A: 16 segs of 1KB, 4/wave
            int seg = wv*4 + s2;
            int row = seg*8 + (l >> 3);
            int cs = (l & 7) ^ (row & 7);
            gload16((char*)As + (size_t)buf*16384 + seg*1024,
                    &X[(size_t)(i0+row)*DIM + kc + cs*4]);
        }
        #pragma unroll
        for (int s2 = 0; s2 < 2; ++s2) {          // B: 8 segs of 1KB, 2/wave
            int seg = wv*2 + s2;
            int col = seg*16 + (l >> 2);
            int cs = (l & 3) ^ (col & 3);
            gload16((char*)Bs + (size_t)buf*8192 + seg*1024,
                    &Bbf[(size_t)(j0+col)*DIM + kc + cs*8]);
        }
    };

    f32x4 acc[4][4];
    #pragma unroll
    for (int a = 0; a < 4; ++a)
        #pragma unroll
        for (int b = 0; b < 4; ++b) acc[a][b] = (f32x4){0.f,0.f,0.f,0.f};

    stage(0, 0);
    __syncthreads();
    for (int t = 0; t < 16; ++t) {
        int cur = t & 1;
        if (t < 15) stage(cur ^ 1, (t+1)*32);
        short8 a8[4], b8[4];
        #pragma unroll
        for (int rt = 0; rt < 4; ++rt) {
            int row = wrow + rt*16 + lr;
            const char* base = (const char*)As + (size_t)cur*16384 + row*128;
            int c1 = (2*h)     ^ (row & 7);
            int c2 = (2*h + 1) ^ (row & 7);
            float4 fa = *reinterpret_cast<const float4*>(base + c1*16);
            float4 fb = *reinterpret_cast<const float4*>(base + c2*16);
            short8 tt;
            tt[0]=(short)f2bf(fa.x); tt[1]=(short)f2bf(fa.y);
            tt[2]=(short)f2bf(fa.z); tt[3]=(short)f2bf(fa.w);
            tt[4]=(short)f2bf(fb.x); tt[5]=(short)f2bf(fb.y);
            tt[6]=(short)f2bf(fb.z); tt[7]=(short)f2bf(fb.w);
            a8[rt] = tt;
        }
        #pragma unroll
        for (int ct = 0; ct < 4; ++ct) {
            int col = wcol + ct*16 + lr;
            int c = h ^ (col & 3);
            b8[ct] = *reinterpret_cast<const short8*>(
                (const char*)Bs + (size_t)cur*8192 + col*64 + c*16);
        }
        #pragma unroll
        for (int rt = 0; rt < 4; ++rt)
            #pragma unroll
            for (int ct = 0; ct < 4; ++ct)
                acc[rt][ct] = __builtin_amdgcn_mfma_f32_16x16x32_bf16(a8[rt], b8[ct], acc[rt][ct], 0, 0, 0);
        __syncthreads();
    }

    // epilogue: rowdot (fp32 X reload, coalesced) + GBbf store for z even
    #pragma unroll
    for (int rt = 0; rt < 4; ++rt) {
        #pragma unroll
        for (int r = 0; r < 4; ++r) {
            int row = wrow + rt*16 + h*4 + r;
            float v = 0.f;
            #pragma unroll
            for (int ct = 0; ct < 4; ++ct) {
                int col = wcol + ct*16 + lr;
                float cv = acc[rt][ct][r];
                float xv = X[(size_t)(i0+row)*DIM + j0 + col];
                v = fmaf(cv, xv, v);
                if ((z & 1) == 0)
                    GBbf[((size_t)((z>>1)*SEQ + i0 + row))*DIM + j0 + col] = f2bf(cv);
            }
            v += __shfl_xor(v, 1); v += __shfl_xor(v, 2);
            v += __shfl_xor(v, 4); v += __shfl_xor(v, 8);
            if (lr == 0) atomicAdd(&pX[(size_t)z*SEQ + i0 + row], 0.5f*v);
        }
    }
}

// ---------------- band via MFMA: cross = PBbf @ Ybf^T on 49 diagonals; dist & K ----------------
__launch_bounds__(64)
__global__ void kband2(const ushort* __restrict__ GBbf, const ushort* __restrict__ Qbf,
                       const float* __restrict__ pX,
                       float* __restrict__ Kb, float* __restrict__ Db) {
    int g = blockIdx.y;
    int i0 = blockIdx.x * 16;
    int l = threadIdx.x;
    const ushort* A = GBbf + (size_t)g*SEQ*DIM;
    const ushort* Y = Qbf  + (size_t)g*SEQ*DIM;
    const float* pM = pX + (size_t)(2*g)*SEQ;
    const float* qM = pX + (size_t)(2*g+1)*SEQ;
    float* Kbg = Kb + (size_t)g*NDIAG*VSTR;
    float* Dbg = Db + (size_t)g*NDIAG*VSTR;
    int jbase = i0 - BW;
    int arow = i0 + (l & 15);
    int koff = (l >> 4) * 8;
    int jcl[4];
    #pragma unroll
    for (int ct = 0; ct < 4; ++ct) {
        int j = jbase + ct*16 + (l & 15);
        jcl[ct] = min(max(j, 0), SEQ-1);
    }
    f32x4 acc[4];
    #pragma unroll
    for (int ct = 0; ct < 4; ++ct) acc[ct] = (f32x4){0.f,0.f,0.f,0.f};
    #pragma unroll
    for (int ks = 0; ks < 16; ++ks) {
        int kk = ks*32 + koff;
        short8 af = *reinterpret_cast<const short8*>(&A[(size_t)arow*DIM + kk]);
        #pragma unroll
        for (int ct = 0; ct < 4; ++ct) {
            short8 bf = *reinterpret_cast<const short8*>(&Y[(size_t)jcl[ct]*DIM + kk]);
            acc[ct] = __builtin_amdgcn_mfma_f32_16x16x32_bf16(af, bf, acc[ct], 0, 0, 0);
        }
    }
    #pragma unroll
    for (int ct = 0; ct < 4; ++ct) {
        #pragma unroll
        for (int r = 0; r < 4; ++r) {
            int i = i0 + (l >> 4)*4 + r;
            int j = jbase + ct*16 + (l & 15);
            int d = j - i;
            if (d >= -BW && d <= BW && j >= 0 && j < SEQ) {
                float dist = pM[i] + qM[j] - acc[ct][r];
                float fd = (float)d;
                float rel = fd * (1.0f/4096.0f);
                float cd = -0.91893853f - 0.25f*fd*fd + 1e-4f/(rel*rel + 1.0f);
                float Kv = expf(cd - dist*1e-3f);
                Dbg[(size_t)(d + BW)*VSTR + VOFF + i] = dist;
                Kbg[(size_t)(d + BW)*VSTR + VOFF + i] = Kv;
            }
        }
    }
}

// ---------------- Sinkhorn: fused banded matvec chain with halo compute ----
// T-step: out[j] = beta_j / sum_idx Kb[idx][j-idx+BW]*in[j-idx+BW]; N-step: out[i]=alpha_i/sum Kb[idx][i]*in[i+idx-BW]
// vstep: store to v slot (+ LDS vsave). ustep: store to u slot. cstep (last step only): crit vs vsave.
__launch_bounds__(256)
__global__ void ksink(const float* __restrict__ Kb, float* __restrict__ vecs,
                      float* __restrict__ sc,
                      int nsteps, int firstT, int alphaInit,
                      int vstep, int ustep, int cstep, int gated, int inSlot, int outSlot) {
    int g = blockIdx.y;
    if (gated && sc[g] < 1e-5f) return;   // early-converged: freeze u,v
    const float* Kbg = Kb + (size_t)g * NDIAG * VSTR;
    int r0 = blockIdx.x * 256;
    int ext = 24 * nsteps;
    __shared__ float bufA[768];
    __shared__ float bufB[768];
    __shared__ float vsave[768];
    __shared__ float red[256];
    float* bin = bufA;
    float* bout = bufB;
    int base = r0 - ext;
    int range0 = 256 + 2*ext;
    const float* vin = vecs + (size_t)(inSlot*2 + g) * VSTR;
    for (int L = threadIdx.x; L < range0; L += 256) {
        int gr = base + L;
        float v;
        if (alphaInit) v = (gr >= 0 && gr < SEQ) ? (gr+1)*INV_N : 0.f;
        else v = vin[VOFF + gr];
        bufA[L] = v;
    }
    __syncthreads();
    float critloc = 0.f;
    for (int m = 0; m < nsteps; ++m) {
        int e = 24 * (nsteps - 1 - m);
        int lo = ext - e;
        int cnt = 256 + 2*e;
        int typeT = firstT ^ (m & 1);
        for (int t = threadIdx.x; t < cnt; t += 256) {
            int L = lo + t;
            int gr = base + L;
            float s = 0.f;
            if (typeT) {
                #pragma unroll
                for (int idx = 0; idx < NDIAG; ++idx)
                    s = fmaf(Kbg[(size_t)idx*VSTR + VOFF + gr - idx + BW], bin[L - idx + BW], s);
            } else {
                #pragma unroll
                for (int idx = 0; idx < NDIAG; ++idx)
                    s = fmaf(Kbg[(size_t)idx*VSTR + VOFF + gr], bin[L + idx - BW], s);
            }
            bool valid = (gr >= 0 && gr < SEQ);
            float ab = (gr+1) * INV_N;     // alpha == beta (m==n)
            float o = valid ? ab / s : 0.f;
            bout[L] = o;
            if (m == vstep && valid) {
                vecs[(size_t)(4 + g)*VSTR + VOFF + gr] = o;      // v slot
                vsave[L] = o;
            }
            if (m == ustep && valid)
                vecs[(size_t)g*VSTR + VOFF + gr] = o;            // u slot
            if (m == cstep && valid)
                critloc += fabsf(vsave[L] * s - ab);
        }
        __syncthreads();
        float* tmp = bin; bin = bout; bout = tmp;
    }
    {
        int gr = r0 + threadIdx.x;
        vecs[(size_t)(outSlot*2 + g)*VSTR + VOFF + gr] = bin[ext + threadIdx.x];
    }
    if (cstep >= 0) {
        red[threadIdx.x] = critloc;
        __syncthreads();
        for (int s = 128; s > 0; s >>= 1) {
            if (threadIdx.x < s) red[threadIdx.x] += red[threadIdx.x + s];
            __syncthreads();
        }
        if (threadIdx.x == 0) atomicAdd(&sc[g], red[0]);
    }
}

// ---------------- final: S_g = sum u_i * K[i,j] * v_j * dist[i,j] over band ----------------
__launch_bounds__(256)
__global__ void kfinal(const float* __restrict__ Kb, const float* __restrict__ Db,
                       const float* __restrict__ vecs, float* __restrict__ sc) {
    int g = blockIdx.y;
    int i = blockIdx.x * 256 + threadIdx.x;
    const float* Kbg = Kb + (size_t)g*NDIAG*VSTR;
    const float* Dbg = Db + (size_t)g*NDIAG*VSTR;
    const float* u = vecs + (size_t)g*VSTR + VOFF;
    const float* v = vecs + (size_t)(4 + g)*VSTR + VOFF;
    float ui = u[i];
    float ss = 0.f;
    #pragma unroll
    for (int idx = 0; idx < NDIAG; ++idx) {
        float kv = Kbg[(size_t)idx*VSTR + VOFF + i];
        float dv = Dbg[(size_t)idx*VSTR + VOFF + i];
        float vv = v[i + idx - BW];
        ss += kv * dv * vv;
    }
    ss *= ui;
    __shared__ float red[256];
    red[threadIdx.x] = ss;
    __syncthreads();
    for (int s = 128; s > 0; s >>= 1) {
        if (threadIdx.x < s) red[threadIdx.x] += red[threadIdx.x + s];
        __syncthreads();
    }
    if (threadIdx.x == 0) atomicAdd(&sc[2+g], red[0]);
}

__global__ void kout(const float* __restrict__ sc, float* __restrict__ out) {
    out[0] = sc[2] - sc[3];
}

extern "C" void kernel_launch(void* const* d_in, const int* in_sizes, int n_in,
                              void* d_out, int out_size, void* d_ws, size_t ws_size,
                              hipStream_t stream) {
    const float* P = (const float*)d_in[0];
    const float* Q = (const float*)d_in[1];
    const float* R = (const float*)d_in[2];
    const float* S = (const float*)d_in[3];
    const float* M = (const float*)d_in[4];
    float* ws = (float*)d_ws;
    if (ws_size < (size_t)WS_FLOATS * sizeof(float)) return;

    float*  Kb  = ws + OFF_KB;
    float*  Db  = ws + OFF_DB;
    float*  vec = ws + OFF_VEC;
    float*  pX  = ws + OFF_PX;
    float*  sc  = ws + OFF_SC;
    ushort* Bbf = (ushort*)(ws + OFF_BBF);
    ushort* Qbf = (ushort*)(ws + OFF_QBF);
    ushort* GBbf= (ushort*)(ws + OFF_GBF);

    // zero bands, vectors, pX, scalars
    hipMemsetAsync(ws + OFF_KB, 0, (size_t)OFF_BBF * sizeof(float), stream);

    ksym2 <<<dim3(1024),     dim3(256), 0, stream>>>(M, Bbf);
    kcvt  <<<dim3(2048, 2),  dim3(256), 0, stream>>>(Q, S, Qbf);
    kgemm3<<<dim3(32, 4, 4), dim3(256), 0, stream>>>(P, Q, R, S, Bbf, GBbf, pX);
    kband2<<<dim3(256, 2),   dim3(64),  0, stream>>>(GBbf, Qbf, pX, Kb, Db);

    // Sinkhorn: 42 banded matvecs in 5 fused launches. Slots: 0=u, 1=y, 2=v.
    // A: T(alpha)->t, N->u1, T->v2(store v), N->u2(store u), T->crit1 + y(out slot1)
    ksink<<<dim3(16,2),256,0,stream>>>(Kb,vec,sc,  5, 1, 1,  2,  3,  4, 0, 0, 1);
    // B,C,D: 10 body matvecs each (N,T alternating), gated on crit1
    ksink<<<dim3(16,2),256,0,stream>>>(Kb,vec,sc, 10, 0, 0, -1, -1, -1, 1, 1, 1);
    ksink<<<dim3(16,2),256,0,stream>>>(Kb,vec,sc, 10, 0, 0, -1, -1, -1, 1, 1, 1);
    ksink<<<dim3(16,2),256,0,stream>>>(Kb,vec,sc, 10, 0, 0, -1, -1, -1, 1, 1, 1);
    // E: 5 body matvecs + check2: T->v2'(store v), N->u2' (out slot0)
    ksink<<<dim3(16,2),256,0,stream>>>(Kb,vec,sc,  7, 0, 0,  5, -1, -1, 1, 1, 0);

    kfinal<<<dim3(16,2), dim3(256), 0, stream>>>(Kb, Db, vec, sc);
    kout  <<<dim3(1),    dim3(1),   0, stream>>>(sc, (float*)d_out);
}